// Round 17
// baseline (390.109 us; speedup 1.0000x reference)
//
#include <hip/hip_runtime.h>
#include <hip/hip_bf16.h>

typedef __attribute__((ext_vector_type(8))) short short8;
typedef __attribute__((ext_vector_type(4))) short short4v;
typedef __attribute__((ext_vector_type(4))) float f32x4;

#define MFMA(a, b, c) __builtin_amdgcn_mfma_f32_16x16x32_bf16(a, b, c, 0, 0, 0)
// XOR-swizzled [64][256] bf16 LDS index (8-elem granule)
#define XS(t, c) (((t) << 8) + ((c) ^ (((t) & 7) << 3)))

extern "C" __device__ float __ocml_native_exp2_f32(float);   // bare v_exp_f32
#define EXP2(x) __ocml_native_exp2_f32(x)

__device__ __forceinline__ unsigned int pk2(float lo, float hi) {
    union { __hip_bfloat162 h2; unsigned int u; } cv;
    cv.h2 = __float22bfloat162_rn(make_float2(lo, hi));
    return cv.u;
}

__device__ __forceinline__ unsigned short f2bf1(float f) {
    unsigned int u = __float_as_uint(f);
    u += 0x7FFFu + ((u >> 16) & 1u);
    return (unsigned short)(u >> 16);
}

__device__ __forceinline__ short4v u2s4(uint2 p) {
    union { uint2 u; short4v s; } t; t.u = p; return t.s;
}

#if __has_builtin(__builtin_amdgcn_mfma_f32_16x16x16bf16_1k)
__device__ __forceinline__ f32x4 mfma16(uint2 a, uint2 b, f32x4 c) {
    return __builtin_amdgcn_mfma_f32_16x16x16bf16_1k(u2s4(a), u2s4(b), c, 0, 0, 0);
}
#else
__device__ __forceinline__ short8 zfrag(uint2 p) {
    union { unsigned int u[4]; short8 s; } t;
    t.u[0] = p.x; t.u[1] = p.y; t.u[2] = 0u; t.u[3] = 0u;
    return t.s;
}
__device__ __forceinline__ f32x4 mfma16(uint2 a, uint2 b, f32x4 c) {
    return MFMA(zfrag(a), zfrag(b), c);
}
#endif

#define SCLF 0.25500566631879443f   // (1/sqrt(32)) * log2(e)

// d_ws layout (elements of unsigned short):
//  [0 .. 196608)    wpk: QKV weights, MFMA-FRAGMENT order; W_q PRE-SCALED by SCLF:
//                   frag f = ((m*8+h)*2+dt)*8+ks, elem = f*512 + lane*8 + j
//                   value = w_qkv[k=ks*32+(lane>>4)*8+j][n=m*256+h*32+dt*16+(lane&15)]
//  [196608..262144) wpj: proj weights, fragment order (cb = column-block 0..15):
//                   frag f = cb*8+ks, elem = f*512 + lane*8 + j
//                   value = w_proj[k=ks*32+(lane>>4)*8+j][n=cb*16+(lane&15)]
__global__ void prep_w(const float* __restrict__ wqkv, const float* __restrict__ wproj,
                       unsigned short* __restrict__ wT) {
    int idx = blockIdx.x * 256 + threadIdx.x;   // 0..262143
    if (idx < 196608) {
        const int frag   = idx >> 9;        // 0..383
        const int within = idx & 511;
        const int lane = within >> 3, j = within & 7;
        const int ks = frag & 7;
        const int dt = (frag >> 3) & 1;
        const int hh = (frag >> 4) & 7;
        const int m  = frag >> 7;
        const int n = m * 256 + hh * 32 + dt * 16 + (lane & 15);
        const int k = ks * 32 + ((lane >> 4) << 3) + j;
        float v = wqkv[k * 768 + n];
        if (m == 0) v *= SCLF;              // fold softmax scale*log2e into W_q
        wT[idx] = f2bf1(v);
    } else {
        const int r = idx - 196608;         // 0..65535
        const int frag = r >> 9;            // 0..127
        const int within = r & 511;
        const int lane = within >> 3, j = within & 7;
        const int ks = frag & 7;
        const int cb = frag >> 3;           // column block 0..15
        const int n = cb * 16 + (lane & 15);
        const int k = ks * 32 + ((lane >> 4) << 3) + j;
        wT[idx] = f2bf1(wproj[k * 256 + n]);
    }
}

// ============ Fused kernel: per-window QKV + attention + proj ============
// 256 thr = 4 waves; wave loops heads {wid, wid+4}. O goes to a SEPARATE 32KB
// LDS region (no overlay barrier). 64KB LDS + ~2 waves/SIMD regs -> 2 blocks/CU
// interleave: one block's MFMA hides the other's barriers/load latency.
// Only 2 barriers per block.
__global__ __launch_bounds__(256, 2)
void winattn(const float* __restrict__ x,
             const float* __restrict__ bqkv,
             const float* __restrict__ bproj,
             const unsigned short* __restrict__ wpk,
             const unsigned short* __restrict__ wpj,
             float* __restrict__ out)
{
    __shared__ unsigned short smem[32768];   // 64KB: x [0,16384) | O [16384,32768)

    const int tid  = threadIdx.x;
    const int wid  = tid >> 6;
    const int lane = tid & 63;
    const int g    = lane >> 4;
    const int q16  = lane & 15;

    // XCD chunking: consecutive windows on the same XCD
    const int bid  = blockIdx.x;
    const int widx = (bid & 7) * 512 + (bid >> 3);
    const int b  = widx >> 10;
    const int wh = (widx >> 5) & 31;
    const int ww = widx & 31;

    // ---- stage x window -> LDS bf16 (swizzled) ----
    {
        const int t  = tid >> 2;           // token 0..63
        const int c0 = (tid & 3) << 3;     // channel base
        const int hr = (wh << 3) + (t >> 3);
        const int wc = (ww << 3) + (t & 7);
        const float* rowp = x + (((size_t)b * 256 + hr) * 256 + wc) * 256;
        #pragma unroll
        for (int u = 0; u < 8; ++u) {
            const int c = c0 + (u << 5);
            const float4 f0 = *reinterpret_cast<const float4*>(rowp + c);
            const float4 f1 = *reinterpret_cast<const float4*>(rowp + c + 4);
            union { unsigned int u4[4]; short8 s; } pv;
            pv.u4[0] = pk2(f0.x, f0.y); pv.u4[1] = pk2(f0.z, f0.w);
            pv.u4[2] = pk2(f1.x, f1.y); pv.u4[3] = pk2(f1.z, f1.w);
            *reinterpret_cast<short8*>(&smem[XS(t, c)]) = pv.s;
        }
    }
    __syncthreads();   // barrier 1 of 2

    const f32x4 fz = {0.f, 0.f, 0.f, 0.f};
    const int loff = lane << 3;

    #pragma unroll 1
    for (int p = 0; p < 2; ++p) {
        const int h = (p << 2) + wid;
        const unsigned short* wh0 = wpk + ((size_t)h << 13);

        // ===== merged QKV, single xf pass per half; bias in C-init =====
        uint2 pq[2][4], pkk[2][4], pv2[2][4];
        #pragma unroll
        for (int half = 0; half < 2; ++half) {
            f32x4 acc[3][2][2];
            #pragma unroll
            for (int dt = 0; dt < 2; ++dt) {
                const float4 bbq = *reinterpret_cast<const float4*>(bqkv + h * 32 + dt * 16 + (g << 2));
                const float4 bbk = *reinterpret_cast<const float4*>(bqkv + 256 + h * 32 + dt * 16 + (g << 2));
                const float bv = bqkv[512 + h * 32 + dt * 16 + q16];
                const f32x4 iq = {bbq.x * SCLF, bbq.y * SCLF, bbq.z * SCLF, bbq.w * SCLF};
                const f32x4 ik = {bbk.x, bbk.y, bbk.z, bbk.w};
                const f32x4 ivv = {bv, bv, bv, bv};
                #pragma unroll
                for (int t2 = 0; t2 < 2; ++t2) {
                    acc[0][dt][t2] = iq; acc[1][dt][t2] = ik; acc[2][dt][t2] = ivv;
                }
            }
            #pragma unroll
            for (int ks = 0; ks < 8; ++ks) {
                const int kc = ks << 5;
                short8 xf[2];
                #pragma unroll
                for (int t2 = 0; t2 < 2; ++t2)
                    xf[t2] = *reinterpret_cast<const short8*>(
                        &smem[XS(((half << 1) + t2) * 16 + q16, kc + (g << 3))]);
                #pragma unroll
                for (int m = 0; m < 3; ++m) {
                    #pragma unroll
                    for (int dt = 0; dt < 2; ++dt) {
                        const short8 wf = *reinterpret_cast<const short8*>(
                            wh0 + (((size_t)m << 16) | (((dt << 3) + ks) << 9)) + loff);
                        #pragma unroll
                        for (int t2 = 0; t2 < 2; ++t2)
                            acc[m][dt][t2] = (m < 2) ? MFMA(wf, xf[t2], acc[m][dt][t2])
                                                     : MFMA(xf[t2], wf, acc[m][dt][t2]);
                    }
                }
            }
            #pragma unroll
            for (int dt = 0; dt < 2; ++dt) {
                #pragma unroll
                for (int t2 = 0; t2 < 2; ++t2) {
                    const int tt = (half << 1) + t2;
                    const f32x4 aq = acc[0][dt][t2];
                    pq[dt][tt]  = make_uint2(pk2(aq[0], aq[1]), pk2(aq[2], aq[3]));
                    const f32x4 ak = acc[1][dt][t2];
                    pkk[dt][tt] = make_uint2(pk2(ak[0], ak[1]), pk2(ak[2], ak[3]));
                    const f32x4 av = acc[2][dt][t2];
                    pv2[dt][tt] = make_uint2(pk2(av[0], av[1]), pk2(av[2], av[3]));
                }
            }
        }

        // ===== S^T = K·Q^T (K=16), exp2 (no max-sub), unnormalized P^T =====
        uint2 ppk[4][4];
        float inv4[4];
        #pragma unroll
        for (int qt = 0; qt < 4; ++qt) {
            f32x4 st[4];
            #pragma unroll
            for (int kt = 0; kt < 4; ++kt) st[kt] = fz;
            #pragma unroll
            for (int dt = 0; dt < 2; ++dt)
                #pragma unroll
                for (int kt = 0; kt < 4; ++kt)
                    st[kt] = mfma16(pkk[dt][kt], pq[dt][qt], st[kt]);
            float sum = 0.f;
            #pragma unroll
            for (int kt = 0; kt < 4; ++kt) {
                const float e0 = EXP2(st[kt][0]), e1 = EXP2(st[kt][1]);
                const float e2 = EXP2(st[kt][2]), e3 = EXP2(st[kt][3]);
                sum += (e0 + e1) + (e2 + e3);
                ppk[kt][qt] = make_uint2(pk2(e0, e1), pk2(e2, e3));
            }
            sum += __shfl_xor(sum, 16);
            sum += __shfl_xor(sum, 32);
            inv4[qt] = 1.f / sum;
        }

        // ===== O^T = V^T·P^T (K=16) =====
        f32x4 ot[2][4];
        #pragma unroll
        for (int dt = 0; dt < 2; ++dt)
            #pragma unroll
            for (int tt = 0; tt < 4; ++tt) ot[dt][tt] = fz;
        #pragma unroll
        for (int kt = 0; kt < 4; ++kt)
            #pragma unroll
            for (int tt = 0; tt < 4; ++tt)
                #pragma unroll
                for (int dt = 0; dt < 2; ++dt)
                    ot[dt][tt] = mfma16(pv2[dt][kt], ppk[kt][tt], ot[dt][tt]);

        // ---- write O (normalized, bf16, swizzled) to separate LDS region ----
        // each wave owns its head's 32 columns; no barrier needed here
        #pragma unroll
        for (int dt = 0; dt < 2; ++dt)
            #pragma unroll
            for (int tt = 0; tt < 4; ++tt) {
                const float iv = inv4[tt];
                const int tok = tt * 16 + q16;
                const int d   = h * 32 + dt * 16 + (g << 2);
                const uint2 pv = make_uint2(pk2(ot[dt][tt][0] * iv, ot[dt][tt][1] * iv),
                                            pk2(ot[dt][tt][2] * iv, ot[dt][tt][3] * iv));
                *reinterpret_cast<uint2*>(&smem[16384 + XS(tok, d)]) = pv;
            }
    }
    __syncthreads();   // barrier 2 of 2: all O columns written

    // ===== proj: wave owns out cols [wid*64, wid*64+64) = 4 nt tiles =====
    f32x4 pacc[4][4];   // [mt][nt]
    {
        #pragma unroll
        for (int nt = 0; nt < 4; ++nt) {
            const float bpv = bproj[wid * 64 + nt * 16 + q16];
            const f32x4 ib = {bpv, bpv, bpv, bpv};
            #pragma unroll
            for (int mt = 0; mt < 4; ++mt) pacc[mt][nt] = ib;
        }
    }
    #pragma unroll
    for (int ks = 0; ks < 8; ++ks) {
        const int kc = ks << 5;
        short8 of[4], wf[4];
        #pragma unroll
        for (int mt = 0; mt < 4; ++mt)
            of[mt] = *reinterpret_cast<const short8*>(
                &smem[16384 + XS(mt * 16 + q16, kc + (g << 3))]);
        #pragma unroll
        for (int nt = 0; nt < 4; ++nt) {
            const int cb = (wid << 2) + nt;     // column block 0..15
            wf[nt] = *reinterpret_cast<const short8*>(
                wpj + (cb << 12) + (ks << 9) + loff);
        }
        #pragma unroll
        for (int mt = 0; mt < 4; ++mt)
            #pragma unroll
            for (int nt = 0; nt < 4; ++nt)
                pacc[mt][nt] = MFMA(of[mt], wf[nt], pacc[mt][nt]);
    }
    // epilogue: tok = mt*16+g*4+r; hr-part = mt*2+(g>>1), wc-part = (g&1)*4+r
    {
        float* obase = out + (((size_t)b * 256 + (wh << 3) + (g >> 1)) * 256
                              + (ww << 3) + ((g & 1) << 2)) * 256 + wid * 64 + q16;
        #pragma unroll
        for (int mt = 0; mt < 4; ++mt)
            #pragma unroll
            for (int r = 0; r < 4; ++r)
                #pragma unroll
                for (int nt = 0; nt < 4; ++nt)
                    obase[mt * 131072 + r * 256 + nt * 16] = pacc[mt][nt][r];
    }
}

extern "C" void kernel_launch(void* const* d_in, const int* in_sizes, int n_in,
                              void* d_out, int out_size, void* d_ws, size_t ws_size,
                              hipStream_t stream) {
    const float* x     = (const float*)d_in[0];
    const float* wqkv  = (const float*)d_in[1];
    const float* bqkv  = (const float*)d_in[2];
    const float* wproj = (const float*)d_in[3];
    const float* bproj = (const float*)d_in[4];
    float* out = (float*)d_out;
    unsigned short* wT = (unsigned short*)d_ws;   // 524288 bytes used

    prep_w<<<1024, 256, 0, stream>>>(wqkv, wproj, wT);
    winattn<<<4096, 256, 0, stream>>>(x, bqkv, bproj, wT, wT + 196608, out);
}

// Round 18
// 276.759 us; speedup vs baseline: 1.4096x; 1.4096x over previous
//
#include <hip/hip_runtime.h>
#include <hip/hip_bf16.h>

typedef __attribute__((ext_vector_type(8))) short short8;
typedef __attribute__((ext_vector_type(4))) short short4v;
typedef __attribute__((ext_vector_type(4))) float f32x4;

#define MFMA(a, b, c) __builtin_amdgcn_mfma_f32_16x16x32_bf16(a, b, c, 0, 0, 0)
// XOR-swizzled [64][256] bf16 LDS index (8-elem granule)
#define XS(t, c) (((t) << 8) + ((c) ^ (((t) & 7) << 3)))

extern "C" __device__ float __ocml_native_exp2_f32(float);   // bare v_exp_f32
#define EXP2(x) __ocml_native_exp2_f32(x)

__device__ __forceinline__ unsigned int pk2(float lo, float hi) {
    union { __hip_bfloat162 h2; unsigned int u; } cv;
    cv.h2 = __float22bfloat162_rn(make_float2(lo, hi));
    return cv.u;
}

__device__ __forceinline__ unsigned short f2bf1(float f) {
    unsigned int u = __float_as_uint(f);
    u += 0x7FFFu + ((u >> 16) & 1u);
    return (unsigned short)(u >> 16);
}

__device__ __forceinline__ short4v u2s4(uint2 p) {
    union { uint2 u; short4v s; } t; t.u = p; return t.s;
}

#if __has_builtin(__builtin_amdgcn_mfma_f32_16x16x16bf16_1k)
__device__ __forceinline__ f32x4 mfma16(uint2 a, uint2 b, f32x4 c) {
    return __builtin_amdgcn_mfma_f32_16x16x16bf16_1k(u2s4(a), u2s4(b), c, 0, 0, 0);
}
#else
__device__ __forceinline__ short8 zfrag(uint2 p) {
    union { unsigned int u[4]; short8 s; } t;
    t.u[0] = p.x; t.u[1] = p.y; t.u[2] = 0u; t.u[3] = 0u;
    return t.s;
}
__device__ __forceinline__ f32x4 mfma16(uint2 a, uint2 b, f32x4 c) {
    return MFMA(zfrag(a), zfrag(b), c);
}
#endif

#define SCLF 0.25500566631879443f   // (1/sqrt(32)) * log2(e)

// d_ws layout (elements of unsigned short):
//  [0 .. 196608)    wpk: QKV weights, MFMA-FRAGMENT order; W_q PRE-SCALED by SCLF:
//                   frag f = ((m*8+h)*2+dt)*8+ks, elem = f*512 + lane*8 + j
//                   value = w_qkv[k=ks*32+(lane>>4)*8+j][n=m*256+h*32+dt*16+(lane&15)]
//  [196608..262144) wpj: proj weights, fragment order:
//                   frag f = (h*2+nt)*8+ks, elem = f*512 + lane*8 + j
//                   value = w_proj[k=ks*32+(lane>>4)*8+j][n=h*32+nt*16+(lane&15)]
__global__ void prep_w(const float* __restrict__ wqkv, const float* __restrict__ wproj,
                       unsigned short* __restrict__ wT) {
    int idx = blockIdx.x * 256 + threadIdx.x;   // 0..262143
    if (idx < 196608) {
        const int frag   = idx >> 9;        // 0..383
        const int within = idx & 511;
        const int lane = within >> 3, j = within & 7;
        const int ks = frag & 7;
        const int dt = (frag >> 3) & 1;
        const int hh = (frag >> 4) & 7;
        const int m  = frag >> 7;
        const int n = m * 256 + hh * 32 + dt * 16 + (lane & 15);
        const int k = ks * 32 + ((lane >> 4) << 3) + j;
        float v = wqkv[k * 768 + n];
        if (m == 0) v *= SCLF;              // fold softmax scale*log2e into W_q
        wT[idx] = f2bf1(v);
    } else {
        const int r = idx - 196608;         // 0..65535
        const int frag = r >> 9;            // 0..127
        const int within = r & 511;
        const int lane = within >> 3, j = within & 7;
        const int ks = frag & 7;
        const int nt = (frag >> 3) & 1;
        const int hh = frag >> 4;
        const int n = hh * 32 + nt * 16 + (lane & 15);
        const int k = ks * 32 + ((lane >> 4) << 3) + j;
        wT[idx] = f2bf1(wproj[k * 256 + n]);
    }
}

// ============ Fused kernel: per-window QKV + attention + proj ============
// R16 configuration (512 thr, wave = head, fused proj) with O in a SEPARATE
// 32KB LDS region -> the x-read/O-overlay barrier is deleted (3 -> 2 barriers).
// Residency is register-bound (1 block/CU) so the extra LDS is free.
__global__ __launch_bounds__(512, 2)
void winattn(const float* __restrict__ x,
             const float* __restrict__ bqkv,
             const float* __restrict__ bproj,
             const unsigned short* __restrict__ wpk,
             const unsigned short* __restrict__ wpj,
             float* __restrict__ out)
{
    __shared__ unsigned short smem[32768];   // 64KB: x [0,16384) | O [16384,32768)

    const int tid  = threadIdx.x;
    const int h    = tid >> 6;        // wave == head
    const int lane = tid & 63;
    const int g    = lane >> 4;
    const int q16  = lane & 15;

    // XCD chunking: consecutive windows on the same XCD
    const int bid  = blockIdx.x;
    const int widx = (bid & 7) * 512 + (bid >> 3);
    const int b  = widx >> 10;
    const int wh = (widx >> 5) & 31;
    const int ww = widx & 31;

    // ---- stage x window -> LDS bf16 (swizzled); 512 threads ----
    {
        const int t  = tid >> 3;              // token 0..63
        const int c0 = (tid & 7) << 3;        // channel base
        const int hr = (wh << 3) + (t >> 3);
        const int wc = (ww << 3) + (t & 7);
        const float* rowp = x + (((size_t)b * 256 + hr) * 256 + wc) * 256;
        #pragma unroll
        for (int u = 0; u < 4; ++u) {
            const int c = c0 + (u << 6);
            const float4 f0 = *reinterpret_cast<const float4*>(rowp + c);
            const float4 f1 = *reinterpret_cast<const float4*>(rowp + c + 4);
            union { unsigned int u4[4]; short8 s; } pv;
            pv.u4[0] = pk2(f0.x, f0.y); pv.u4[1] = pk2(f0.z, f0.w);
            pv.u4[2] = pk2(f1.x, f1.y); pv.u4[3] = pk2(f1.z, f1.w);
            *reinterpret_cast<short8*>(&smem[XS(t, c)]) = pv.s;
        }
    }
    __syncthreads();   // barrier 1 of 2

    const unsigned short* wh0 = wpk + ((size_t)h << 13);   // head base; m stride 1<<16
    const int loff = lane << 3;

    // ===== merged QKV, single xf pass per half; bias in C-init =====
    uint2 pq[2][4], pkk[2][4], pv2[2][4];
    #pragma unroll
    for (int half = 0; half < 2; ++half) {
        f32x4 acc[3][2][2];
        #pragma unroll
        for (int dt = 0; dt < 2; ++dt) {
            const float4 bbq = *reinterpret_cast<const float4*>(bqkv + h * 32 + dt * 16 + (g << 2));
            const float4 bbk = *reinterpret_cast<const float4*>(bqkv + 256 + h * 32 + dt * 16 + (g << 2));
            const float bv = bqkv[512 + h * 32 + dt * 16 + q16];
            const f32x4 iq = {bbq.x * SCLF, bbq.y * SCLF, bbq.z * SCLF, bbq.w * SCLF};
            const f32x4 ik = {bbk.x, bbk.y, bbk.z, bbk.w};
            const f32x4 ivv = {bv, bv, bv, bv};
            #pragma unroll
            for (int t2 = 0; t2 < 2; ++t2) {
                acc[0][dt][t2] = iq; acc[1][dt][t2] = ik; acc[2][dt][t2] = ivv;
            }
        }
        #pragma unroll
        for (int ks = 0; ks < 8; ++ks) {
            const int kc = ks << 5;
            short8 xf[2];
            #pragma unroll
            for (int t2 = 0; t2 < 2; ++t2)
                xf[t2] = *reinterpret_cast<const short8*>(
                    &smem[XS(((half << 1) + t2) * 16 + q16, kc + (g << 3))]);
            #pragma unroll
            for (int m = 0; m < 3; ++m) {
                #pragma unroll
                for (int dt = 0; dt < 2; ++dt) {
                    const short8 wf = *reinterpret_cast<const short8*>(
                        wh0 + (((size_t)m << 16) | (((dt << 3) + ks) << 9)) + loff);
                    #pragma unroll
                    for (int t2 = 0; t2 < 2; ++t2)
                        acc[m][dt][t2] = (m < 2) ? MFMA(wf, xf[t2], acc[m][dt][t2])
                                                 : MFMA(xf[t2], wf, acc[m][dt][t2]);
                }
            }
        }
        #pragma unroll
        for (int dt = 0; dt < 2; ++dt) {
            #pragma unroll
            for (int t2 = 0; t2 < 2; ++t2) {
                const int tt = (half << 1) + t2;
                const f32x4 aq = acc[0][dt][t2];
                pq[dt][tt]  = make_uint2(pk2(aq[0], aq[1]), pk2(aq[2], aq[3]));
                const f32x4 ak = acc[1][dt][t2];
                pkk[dt][tt] = make_uint2(pk2(ak[0], ak[1]), pk2(ak[2], ak[3]));
                const f32x4 av = acc[2][dt][t2];
                pv2[dt][tt] = make_uint2(pk2(av[0], av[1]), pk2(av[2], av[3]));
            }
        }
    }

    // ===== S^T = K·Q^T (K=16), exp2 (no max-sub), unnormalized P^T =====
    const f32x4 fz = {0.f, 0.f, 0.f, 0.f};
    uint2 ppk[4][4];
    float inv4[4];
    #pragma unroll
    for (int qt = 0; qt < 4; ++qt) {
        f32x4 st[4];
        #pragma unroll
        for (int kt = 0; kt < 4; ++kt) st[kt] = fz;
        #pragma unroll
        for (int dt = 0; dt < 2; ++dt)
            #pragma unroll
            for (int kt = 0; kt < 4; ++kt)
                st[kt] = mfma16(pkk[dt][kt], pq[dt][qt], st[kt]);
        float sum = 0.f;
        #pragma unroll
        for (int kt = 0; kt < 4; ++kt) {
            const float e0 = EXP2(st[kt][0]), e1 = EXP2(st[kt][1]);
            const float e2 = EXP2(st[kt][2]), e3 = EXP2(st[kt][3]);
            sum += (e0 + e1) + (e2 + e3);
            ppk[kt][qt] = make_uint2(pk2(e0, e1), pk2(e2, e3));
        }
        sum += __shfl_xor(sum, 16);
        sum += __shfl_xor(sum, 32);
        inv4[qt] = 1.f / sum;
    }

    // ===== O^T = V^T·P^T (K=16) =====
    f32x4 ot[2][4];    // lane: O[tok=tt*16+q16][d=h*32+dt*16+g*4+r]
    #pragma unroll
    for (int dt = 0; dt < 2; ++dt)
        #pragma unroll
        for (int tt = 0; tt < 4; ++tt) ot[dt][tt] = fz;
    #pragma unroll
    for (int kt = 0; kt < 4; ++kt)
        #pragma unroll
        for (int tt = 0; tt < 4; ++tt)
            #pragma unroll
            for (int dt = 0; dt < 2; ++dt)
                ot[dt][tt] = mfma16(pv2[dt][kt], ppk[kt][tt], ot[dt][tt]);

    // ---- O write (normalized, bf16, swizzled) to SEPARATE LDS region ----
    // each wave owns its head's 32 columns; x region untouched -> no barrier here
    #pragma unroll
    for (int dt = 0; dt < 2; ++dt)
        #pragma unroll
        for (int tt = 0; tt < 4; ++tt) {
            const float iv = inv4[tt];
            const int tok = tt * 16 + q16;
            const int d   = h * 32 + dt * 16 + (g << 2);
            const uint2 pv = make_uint2(pk2(ot[dt][tt][0] * iv, ot[dt][tt][1] * iv),
                                        pk2(ot[dt][tt][2] * iv, ot[dt][tt][3] * iv));
            *reinterpret_cast<uint2*>(&smem[16384 + XS(tok, d)]) = pv;
        }
    __syncthreads();   // barrier 2 of 2: all O columns written

    // ===== proj: out[:, h*32..h*32+32) = O[64][256] @ wproj + bias (in C-init) =====
    f32x4 pacc[4][2];
    {
        float bpv[2];
        #pragma unroll
        for (int nt = 0; nt < 2; ++nt) bpv[nt] = bproj[h * 32 + nt * 16 + q16];
        #pragma unroll
        for (int mt = 0; mt < 4; ++mt)
            #pragma unroll
            for (int nt = 0; nt < 2; ++nt) {
                const f32x4 ib = {bpv[nt], bpv[nt], bpv[nt], bpv[nt]};
                pacc[mt][nt] = ib;
            }
    }
    const unsigned short* wpjh = wpj + ((size_t)h << 13);   // 16 frags * 512
    #pragma unroll
    for (int ks = 0; ks < 8; ++ks) {
        const int kc = ks << 5;
        short8 of[4], wf[2];
        #pragma unroll
        for (int mt = 0; mt < 4; ++mt)
            of[mt] = *reinterpret_cast<const short8*>(
                &smem[16384 + XS(mt * 16 + q16, kc + (g << 3))]);
        #pragma unroll
        for (int nt = 0; nt < 2; ++nt)
            wf[nt] = *reinterpret_cast<const short8*>(wpjh + (((nt << 3) + ks) << 9) + loff);
        #pragma unroll
        for (int mt = 0; mt < 4; ++mt)
            #pragma unroll
            for (int nt = 0; nt < 2; ++nt)
                pacc[mt][nt] = MFMA(of[mt], wf[nt], pacc[mt][nt]);
    }
    // epilogue: tok = mt*16+g*4+r; hr-part = mt*2+(g>>1), wc-part = (g&1)*4+r
    {
        float* obase = out + (((size_t)b * 256 + (wh << 3) + (g >> 1)) * 256
                              + (ww << 3) + ((g & 1) << 2)) * 256 + h * 32 + q16;
        #pragma unroll
        for (int mt = 0; mt < 4; ++mt)
            #pragma unroll
            for (int r = 0; r < 4; ++r)
                #pragma unroll
                for (int nt = 0; nt < 2; ++nt)
                    obase[mt * 131072 + r * 256 + nt * 16] = pacc[mt][nt][r];
    }
}

extern "C" void kernel_launch(void* const* d_in, const int* in_sizes, int n_in,
                              void* d_out, int out_size, void* d_ws, size_t ws_size,
                              hipStream_t stream) {
    const float* x     = (const float*)d_in[0];
    const float* wqkv  = (const float*)d_in[1];
    const float* bqkv  = (const float*)d_in[2];
    const float* wproj = (const float*)d_in[3];
    const float* bproj = (const float*)d_in[4];
    float* out = (float*)d_out;
    unsigned short* wT = (unsigned short*)d_ws;   // 524288 bytes used

    prep_w<<<1024, 256, 0, stream>>>(wqkv, wproj, wT);
    winattn<<<4096, 512, 0, stream>>>(x, bqkv, bproj, wT, wT + 196608, out);
}